// Round 14
// baseline (91.882 us; speedup 1.0000x reference)
//
#include <hip/hip_runtime.h>
#include <stdint.h>

#define C   32
#define H   160
#define W   160
#define NB  32
#define HW  (H * W)          // 25600
#define CHW (C * HW)         // 819200
#define NPIX (NB * HW)       // 819200
#define XBOFF 448            // xbits offset in d_ws (u32 units)

// d_ws layout (uint32 units):
// [0,288)    w3bits [oc*9 + kh*3 + kw], bit ic = (w3<0)
// [288,320)  w1bits [oc], bit ic = (w1<0)
// f[320,352) inv3   f[352,384) sh3 = b3 - m3*inv3
// f[384,416) inv1   f[416,448) sh1 = b1 - m1*inv1
// [448,448+NPIX) xbits [n*HW + h*W + w], bit c = (x<0)

__global__ void pack_params(const float* __restrict__ w3,
                            const float* __restrict__ g3, const float* __restrict__ b3,
                            const float* __restrict__ m3, const float* __restrict__ v3,
                            const float* __restrict__ w1,
                            const float* __restrict__ g1, const float* __restrict__ b1,
                            const float* __restrict__ m1, const float* __restrict__ v1,
                            uint32_t* __restrict__ wsu) {
    int t = threadIdx.x;
    if (t < 288) {
        int oc = t / 9, tap = t % 9;
        uint32_t bits = 0;
#pragma unroll
        for (int ic = 0; ic < 32; ++ic)
            bits |= (w3[oc * 288 + ic * 9 + tap] < 0.0f) ? (1u << ic) : 0u;
        wsu[t] = bits;
    } else if (t < 320) {
        int oc = t - 288;
        uint32_t bits = 0;
#pragma unroll
        for (int ic = 0; ic < 32; ++ic)
            bits |= (w1[oc * 32 + ic] < 0.0f) ? (1u << ic) : 0u;
        wsu[288 + oc] = bits;
        float* f = (float*)wsu;
        float inv3 = g3[oc] * rsqrtf(v3[oc] + 1e-5f);
        f[320 + oc] = inv3;
        f[352 + oc] = b3[oc] - m3[oc] * inv3;
        float inv1 = g1[oc] * rsqrtf(v1[oc] + 1e-5f);
        f[384 + oc] = inv1;
        f[416 + oc] = b1[oc] - m1[oc] * inv1;
    }
}

__global__ __launch_bounds__(256) void pack_x(const float* __restrict__ x,
                                              uint32_t* __restrict__ xbits) {
    int i = blockIdx.x * blockDim.x + threadIdx.x;   // quad index
    if (i >= NPIX / 4) return;
    int p = i * 4;
    int n = p / HW;
    int r = p % HW;
    const float* xp = x + n * CHW + r;
    uint32_t b0 = 0, b1 = 0, b2 = 0, b3 = 0;
#pragma unroll
    for (int c = 0; c < 32; ++c) {
        float4 v = *reinterpret_cast<const float4*>(xp + c * HW);
        b0 |= (v.x < 0.0f) ? (1u << c) : 0u;
        b1 |= (v.y < 0.0f) ? (1u << c) : 0u;
        b2 |= (v.z < 0.0f) ? (1u << c) : 0u;
        b3 |= (v.w < 0.0f) ? (1u << c) : 0u;
    }
    *reinterpret_cast<uint4*>(xbits + p) = make_uint4(b0, b1, b2, b3);
}

// Block = 256 consecutive pixels of one image (HW % 256 == 0).
// Phase A: cooperative float4 x loads -> LDS (1 KB per wave-instruction).
// Phase B: R11-proven scalar per-pixel body; residual x from LDS; z written
//          back into the same LDS slot (read-then-overwrite by same thread).
// Phase C: cooperative float4 z stores from LDS (1 KB per wave-instruction).
// Border pixels wrong (clamped neighborhood) -> overwritten by border_fix.
__global__ __launch_bounds__(256) void fused_main(const float* __restrict__ x,
                                                  const uint32_t* __restrict__ wsu,
                                                  float* __restrict__ out) {
    __shared__ float xz[C][256];     // 32 KB; holds x in phase B, z after
    const float* wf = (const float*)wsu;
    int t    = threadIdx.x;
    int pix0 = blockIdx.x * 256;
    int n    = pix0 / HW;
    int off0 = pix0 - n * HW;

    // ---- phase A: x -> LDS, 16 B/lane ----
    {
        int q  = t & 63;             // quad within block (wave-contiguous)
        int c0 = (t >> 6) * 8;       // 8 channels per thread
        const float* xb = x + n * CHW + off0 + 4 * q;
#pragma unroll
        for (int j = 0; j < 8; ++j) {
            int ch = c0 + j;
            float4 v = *reinterpret_cast<const float4*>(xb + ch * HW);
            *reinterpret_cast<float4*>(&xz[ch][4 * q]) = v;
        }
    }
    __syncthreads();

    // ---- phase B: conv + BN + residual + 1x1 block (scalar, proven) ----
    {
        int rem = off0 + t;
        int h   = rem / W;
        int w   = rem % W;

        const uint32_t* xbn = wsu + XBOFF + n * HW;
        int hm1 = (h > 0) ? h - 1 : 0;
        int hp1 = (h < H - 1) ? h + 1 : H - 1;
        int wm1 = (w > 0) ? w - 1 : 0;
        int wp1 = (w < W - 1) ? w + 1 : W - 1;

        uint32_t nb[3][3];
        {
            const uint32_t* r0 = xbn + hm1 * W;
            const uint32_t* r1 = xbn + h   * W;
            const uint32_t* r2 = xbn + hp1 * W;
            nb[0][0] = r0[wm1]; nb[0][1] = r0[w]; nb[0][2] = r0[wp1];
            nb[1][0] = r1[wm1]; nb[1][1] = r1[w]; nb[1][2] = r1[wp1];
            nb[2][0] = r2[wm1]; nb[2][1] = r2[w]; nb[2][2] = r2[wp1];
        }

        float y[32];
        uint32_t yb = 0;
#pragma unroll
        for (int oc = 0; oc < 32; ++oc) {
            int s = 0;
#pragma unroll
            for (int r = 0; r < 3; ++r)
#pragma unroll
                for (int c = 0; c < 3; ++c)
                    s += __popc(nb[r][c] ^ wsu[oc * 9 + r * 3 + c]);  // s_load
            float sc = wf[320 + oc], sh = wf[352 + oc];               // s_load
            y[oc] = fmaf((float)(288 - 2 * s), sc, sh) + xz[oc][t];
            yb |= (y[oc] < 0.0f) ? (1u << oc) : 0u;
        }

#pragma unroll
        for (int oc = 0; oc < 32; ++oc) {
            float sc = wf[384 + oc], sh = wf[416 + oc];
            int cc = 32 - 2 * __popc(yb ^ wsu[288 + oc]);
            xz[oc][t] = fmaf((float)cc, sc, sh) + y[oc];   // overwrite with z
        }
    }
    __syncthreads();

    // ---- phase C: z -> out, 16 B/lane ----
    {
        int q  = t & 63;
        int c0 = (t >> 6) * 8;
        float* ob = out + n * CHW + off0 + 4 * q;
#pragma unroll
        for (int j = 0; j < 8; ++j) {
            int ch = c0 + j;
            float4 v = *reinterpret_cast<const float4*>(&xz[ch][4 * q]);
            *reinterpret_cast<float4*>(ob + ch * HW) = v;
        }
    }
}

// Recompute border pixels exactly (true zero-padding masks) from packed bits.
// 636 border pixels per image * 32 images = 20352 threads.
__global__ __launch_bounds__(256) void border_fix(const float* __restrict__ x,
                                                  const uint32_t* __restrict__ wsu,
                                                  float* __restrict__ out) {
    const float* wf = (const float*)wsu;
    int t = blockIdx.x * blockDim.x + threadIdx.x;
    if (t >= NB * 636) return;
    int n = t / 636, idx = t % 636;
    int h, w;
    if (idx < 160)      { h = 0;         w = idx; }
    else if (idx < 320) { h = H - 1;     w = idx - 160; }
    else if (idx < 478) { h = idx - 319; w = 0; }       // h = 1..158
    else                { h = idx - 477; w = W - 1; }   // h = 1..158

    const uint32_t* xbn = wsu + XBOFF + n * HW;
    uint32_t nb[3][3];
    int m[3][3];
#pragma unroll
    for (int r = 0; r < 3; ++r) {
        int hh = h + r - 1;
        bool rok = (hh >= 0) && (hh < H);
#pragma unroll
        for (int c = 0; c < 3; ++c) {
            int ww = w + c - 1;
            bool ok = rok && (ww >= 0) && (ww < W);
            m[r][c]  = ok ? -1 : 0;
            nb[r][c] = ok ? xbn[hh * W + ww] : 0u;
        }
    }

    const float* xp = x + n * CHW + h * W + w;
    float y[32];
    uint32_t yb = 0;
#pragma unroll
    for (int oc = 0; oc < 32; ++oc) {
        int s = 0;   // true conv value (masked taps contribute 0)
#pragma unroll
        for (int r = 0; r < 3; ++r) {
#pragma unroll
            for (int c = 0; c < 3; ++c) {
                uint32_t wv = wsu[oc * 9 + r * 3 + c];
                s += (32 - 2 * __popc(nb[r][c] ^ wv)) & m[r][c];
            }
        }
        float sc = wf[320 + oc], sh = wf[352 + oc];
        y[oc] = fmaf((float)s, sc, sh) + xp[oc * HW];
        yb |= (y[oc] < 0.0f) ? (1u << oc) : 0u;
    }
    float* op = out + n * CHW + h * W + w;
#pragma unroll
    for (int oc = 0; oc < 32; ++oc) {
        float sc = wf[384 + oc], sh = wf[416 + oc];
        int cc = 32 - 2 * __popc(yb ^ wsu[288 + oc]);
        op[oc * HW] = fmaf((float)cc, sc, sh) + y[oc];
    }
}

extern "C" void kernel_launch(void* const* d_in, const int* in_sizes, int n_in,
                              void* d_out, int out_size, void* d_ws, size_t ws_size,
                              hipStream_t stream) {
    const float* x  = (const float*)d_in[0];
    const float* w3 = (const float*)d_in[1];
    const float* g3 = (const float*)d_in[2];
    const float* b3 = (const float*)d_in[3];
    const float* m3 = (const float*)d_in[4];
    const float* v3 = (const float*)d_in[5];
    const float* w1 = (const float*)d_in[6];
    const float* g1 = (const float*)d_in[7];
    const float* b1 = (const float*)d_in[8];
    const float* m1 = (const float*)d_in[9];
    const float* v1 = (const float*)d_in[10];
    float* out = (float*)d_out;
    uint32_t* wsu = (uint32_t*)d_ws;

    pack_params<<<1, 320, 0, stream>>>(w3, g3, b3, m3, v3, w1, g1, b1, m1, v1, wsu);
    pack_x<<<NPIX / 4 / 256, 256, 0, stream>>>(x, wsu + XBOFF);
    fused_main<<<NPIX / 256, 256, 0, stream>>>(x, wsu, out);
    border_fix<<<(NB * 636 + 255) / 256, 256, 0, stream>>>(x, wsu, out);
}

// Round 17
// 86.938 us; speedup vs baseline: 1.0569x; 1.0569x over previous
//
#include <hip/hip_runtime.h>
#include <stdint.h>

#define C   32
#define H   160
#define W   160
#define NB  32
#define HW  (H * W)          // 25600
#define CHW (C * HW)         // 819200
#define NPIX (NB * HW)       // 819200
#define XBOFF 448            // xbits offset in d_ws (u32 units)

// d_ws layout (uint32 units):
// [0,288)    w3bits [oc*9 + kh*3 + kw], bit ic = (w3<0)
// [288,320)  w1bits [oc], bit ic = (w1<0)
// f[320,352) inv3   f[352,384) sh3 = b3 - m3*inv3
// f[384,416) inv1   f[416,448) sh1 = b1 - m1*inv1
// [448,448+NPIX) xbits [n*HW + h*W + w], bit c = (x<0)

__global__ void pack_params(const float* __restrict__ w3,
                            const float* __restrict__ g3, const float* __restrict__ b3,
                            const float* __restrict__ m3, const float* __restrict__ v3,
                            const float* __restrict__ w1,
                            const float* __restrict__ g1, const float* __restrict__ b1,
                            const float* __restrict__ m1, const float* __restrict__ v1,
                            uint32_t* __restrict__ wsu) {
    int t = threadIdx.x;
    if (t < 288) {
        int oc = t / 9, tap = t % 9;
        uint32_t bits = 0;
#pragma unroll
        for (int ic = 0; ic < 32; ++ic)
            bits |= (w3[oc * 288 + ic * 9 + tap] < 0.0f) ? (1u << ic) : 0u;
        wsu[t] = bits;
    } else if (t < 320) {
        int oc = t - 288;
        uint32_t bits = 0;
#pragma unroll
        for (int ic = 0; ic < 32; ++ic)
            bits |= (w1[oc * 32 + ic] < 0.0f) ? (1u << ic) : 0u;
        wsu[288 + oc] = bits;
        float* f = (float*)wsu;
        float inv3 = g3[oc] * rsqrtf(v3[oc] + 1e-5f);
        f[320 + oc] = inv3;
        f[352 + oc] = b3[oc] - m3[oc] * inv3;
        float inv1 = g1[oc] * rsqrtf(v1[oc] + 1e-5f);
        f[384 + oc] = inv1;
        f[416 + oc] = b1[oc] - m1[oc] * inv1;
    }
}

__global__ __launch_bounds__(256) void pack_x(const float* __restrict__ x,
                                              uint32_t* __restrict__ xbits) {
    int i = blockIdx.x * blockDim.x + threadIdx.x;   // quad index
    if (i >= NPIX / 4) return;
    int p = i * 4;
    int n = p / HW;
    int r = p % HW;
    const float* xp = x + n * CHW + r;
    uint32_t b0 = 0, b1 = 0, b2 = 0, b3 = 0;
#pragma unroll
    for (int c = 0; c < 32; ++c) {
        float4 v = *reinterpret_cast<const float4*>(xp + c * HW);
        b0 |= (v.x < 0.0f) ? (1u << c) : 0u;
        b1 |= (v.y < 0.0f) ? (1u << c) : 0u;
        b2 |= (v.z < 0.0f) ? (1u << c) : 0u;
        b3 |= (v.w < 0.0f) ? (1u << c) : 0u;
    }
    *reinterpret_cast<uint4*>(xbits + p) = make_uint4(b0, b1, b2, b3);
}

// Block = 256 consecutive pixels of one image (HW % 256 == 0).
// Compute: R11-proven scalar 1 px/thread body (x loads stay 4 B/lane,
// overlapped with compute). Store side only is staged: z -> LDS, one
// barrier, then cooperative float4 stores (1 KB per wave-instruction).
// Border pixels wrong (clamped neighborhood) -> overwritten by border_fix.
__global__ __launch_bounds__(256) void fused_main(const float* __restrict__ x,
                                                  const uint32_t* __restrict__ wsu,
                                                  float* __restrict__ out) {
    __shared__ float xz[C][256];     // 32 KB; z staging
    const float* wf = (const float*)wsu;
    int t    = threadIdx.x;
    int pix0 = blockIdx.x * 256;
    int n    = pix0 / HW;
    int off0 = pix0 - n * HW;

    // ---- compute (verbatim R11 body; z to LDS instead of global) ----
    {
        int rem = off0 + t;
        int h   = rem / W;
        int w   = rem % W;

        const uint32_t* xbn = wsu + XBOFF + n * HW;
        int hm1 = (h > 0) ? h - 1 : 0;
        int hp1 = (h < H - 1) ? h + 1 : H - 1;
        int wm1 = (w > 0) ? w - 1 : 0;
        int wp1 = (w < W - 1) ? w + 1 : W - 1;

        uint32_t nb[3][3];
        {
            const uint32_t* r0 = xbn + hm1 * W;
            const uint32_t* r1 = xbn + h   * W;
            const uint32_t* r2 = xbn + hp1 * W;
            nb[0][0] = r0[wm1]; nb[0][1] = r0[w]; nb[0][2] = r0[wp1];
            nb[1][0] = r1[wm1]; nb[1][1] = r1[w]; nb[1][2] = r1[wp1];
            nb[2][0] = r2[wm1]; nb[2][1] = r2[w]; nb[2][2] = r2[wp1];
        }

        const float* xp = x + n * CHW + h * W + w;
        float y[32];
        uint32_t yb = 0;
#pragma unroll
        for (int oc = 0; oc < 32; ++oc) {
            int s = 0;
#pragma unroll
            for (int r = 0; r < 3; ++r)
#pragma unroll
                for (int c = 0; c < 3; ++c)
                    s += __popc(nb[r][c] ^ wsu[oc * 9 + r * 3 + c]);  // s_load
            float sc = wf[320 + oc], sh = wf[352 + oc];               // s_load
            y[oc] = fmaf((float)(288 - 2 * s), sc, sh) + xp[oc * HW];
            yb |= (y[oc] < 0.0f) ? (1u << oc) : 0u;
        }

#pragma unroll
        for (int oc = 0; oc < 32; ++oc) {
            float sc = wf[384 + oc], sh = wf[416 + oc];
            int cc = 32 - 2 * __popc(yb ^ wsu[288 + oc]);
            xz[oc][t] = fmaf((float)cc, sc, sh) + y[oc];
        }
    }
    __syncthreads();

    // ---- burst store: z -> out, 16 B/lane (1 KB per wave-instruction) ----
    {
        int q  = t & 63;             // quad within block (wave-contiguous)
        int c0 = (t >> 6) * 8;       // 8 channels per thread
        float* ob = out + n * CHW + off0 + 4 * q;
#pragma unroll
        for (int j = 0; j < 8; ++j) {
            int ch = c0 + j;
            float4 v = *reinterpret_cast<const float4*>(&xz[ch][4 * q]);
            *reinterpret_cast<float4*>(ob + ch * HW) = v;
        }
    }
}

// Recompute border pixels exactly (true zero-padding masks) from packed bits.
// 636 border pixels per image * 32 images = 20352 threads.
__global__ __launch_bounds__(256) void border_fix(const float* __restrict__ x,
                                                  const uint32_t* __restrict__ wsu,
                                                  float* __restrict__ out) {
    const float* wf = (const float*)wsu;
    int t = blockIdx.x * blockDim.x + threadIdx.x;
    if (t >= NB * 636) return;
    int n = t / 636, idx = t % 636;
    int h, w;
    if (idx < 160)      { h = 0;         w = idx; }
    else if (idx < 320) { h = H - 1;     w = idx - 160; }
    else if (idx < 478) { h = idx - 319; w = 0; }       // h = 1..158
    else                { h = idx - 477; w = W - 1; }   // h = 1..158

    const uint32_t* xbn = wsu + XBOFF + n * HW;
    uint32_t nb[3][3];
    int m[3][3];
#pragma unroll
    for (int r = 0; r < 3; ++r) {
        int hh = h + r - 1;
        bool rok = (hh >= 0) && (hh < H);
#pragma unroll
        for (int c = 0; c < 3; ++c) {
            int ww = w + c - 1;
            bool ok = rok && (ww >= 0) && (ww < W);
            m[r][c]  = ok ? -1 : 0;
            nb[r][c] = ok ? xbn[hh * W + ww] : 0u;
        }
    }

    const float* xp = x + n * CHW + h * W + w;
    float y[32];
    uint32_t yb = 0;
#pragma unroll
    for (int oc = 0; oc < 32; ++oc) {
        int s = 0;   // true conv value (masked taps contribute 0)
#pragma unroll
        for (int r = 0; r < 3; ++r) {
#pragma unroll
            for (int c = 0; c < 3; ++c) {
                uint32_t wv = wsu[oc * 9 + r * 3 + c];
                s += (32 - 2 * __popc(nb[r][c] ^ wv)) & m[r][c];
            }
        }
        float sc = wf[320 + oc], sh = wf[352 + oc];
        y[oc] = fmaf((float)s, sc, sh) + xp[oc * HW];
        yb |= (y[oc] < 0.0f) ? (1u << oc) : 0u;
    }
    float* op = out + n * CHW + h * W + w;
#pragma unroll
    for (int oc = 0; oc < 32; ++oc) {
        float sc = wf[384 + oc], sh = wf[416 + oc];
        int cc = 32 - 2 * __popc(yb ^ wsu[288 + oc]);
        op[oc * HW] = fmaf((float)cc, sc, sh) + y[oc];
    }
}

extern "C" void kernel_launch(void* const* d_in, const int* in_sizes, int n_in,
                              void* d_out, int out_size, void* d_ws, size_t ws_size,
                              hipStream_t stream) {
    const float* x  = (const float*)d_in[0];
    const float* w3 = (const float*)d_in[1];
    const float* g3 = (const float*)d_in[2];
    const float* b3 = (const float*)d_in[3];
    const float* m3 = (const float*)d_in[4];
    const float* v3 = (const float*)d_in[5];
    const float* w1 = (const float*)d_in[6];
    const float* g1 = (const float*)d_in[7];
    const float* b1 = (const float*)d_in[8];
    const float* m1 = (const float*)d_in[9];
    const float* v1 = (const float*)d_in[10];
    float* out = (float*)d_out;
    uint32_t* wsu = (uint32_t*)d_ws;

    pack_params<<<1, 320, 0, stream>>>(w3, g3, b3, m3, v3, w1, g1, b1, m1, v1, wsu);
    pack_x<<<NPIX / 4 / 256, 256, 0, stream>>>(x, wsu + XBOFF);
    fused_main<<<NPIX / 256, 256, 0, stream>>>(x, wsu, out);
    border_fix<<<(NB * 636 + 255) / 256, 256, 0, stream>>>(x, wsu, out);
}

// Round 18
// 83.621 us; speedup vs baseline: 1.0988x; 1.0397x over previous
//
#include <hip/hip_runtime.h>
#include <stdint.h>

#define C   32
#define H   160
#define W   160
#define NB  32
#define HW  (H * W)          // 25600
#define CHW (C * HW)         // 819200
#define NPIX (NB * HW)       // 819200
#define XBOFF 448            // xbits offset in d_ws (u32 units)

// d_ws layout (uint32 units):
// [0,288)    w3bits [oc*9 + kh*3 + kw], bit ic = (w3<0)
// [288,320)  w1bits [oc], bit ic = (w1<0)
// f[320,352) inv3   f[352,384) sh3 = b3 - m3*inv3
// f[384,416) inv1   f[416,448) sh1 = b1 - m1*inv1
// [448,448+NPIX) xbits [n*HW + h*W + w], bit c = (x<0)

__global__ void pack_params(const float* __restrict__ w3,
                            const float* __restrict__ g3, const float* __restrict__ b3,
                            const float* __restrict__ m3, const float* __restrict__ v3,
                            const float* __restrict__ w1,
                            const float* __restrict__ g1, const float* __restrict__ b1,
                            const float* __restrict__ m1, const float* __restrict__ v1,
                            uint32_t* __restrict__ wsu) {
    int t = threadIdx.x;
    if (t < 288) {
        int oc = t / 9, tap = t % 9;
        uint32_t bits = 0;
#pragma unroll
        for (int ic = 0; ic < 32; ++ic)
            bits |= (w3[oc * 288 + ic * 9 + tap] < 0.0f) ? (1u << ic) : 0u;
        wsu[t] = bits;
    } else if (t < 320) {
        int oc = t - 288;
        uint32_t bits = 0;
#pragma unroll
        for (int ic = 0; ic < 32; ++ic)
            bits |= (w1[oc * 32 + ic] < 0.0f) ? (1u << ic) : 0u;
        wsu[288 + oc] = bits;
        float* f = (float*)wsu;
        float inv3 = g3[oc] * rsqrtf(v3[oc] + 1e-5f);
        f[320 + oc] = inv3;
        f[352 + oc] = b3[oc] - m3[oc] * inv3;
        float inv1 = g1[oc] * rsqrtf(v1[oc] + 1e-5f);
        f[384 + oc] = inv1;
        f[416 + oc] = b1[oc] - m1[oc] * inv1;
    }
}

__global__ __launch_bounds__(256) void pack_x(const float* __restrict__ x,
                                              uint32_t* __restrict__ xbits) {
    int i = blockIdx.x * blockDim.x + threadIdx.x;   // quad index
    if (i >= NPIX / 4) return;
    int p = i * 4;
    int n = p / HW;
    int r = p % HW;
    const float* xp = x + n * CHW + r;
    uint32_t b0 = 0, b1 = 0, b2 = 0, b3 = 0;
#pragma unroll
    for (int c = 0; c < 32; ++c) {
        float4 v = *reinterpret_cast<const float4*>(xp + c * HW);
        b0 |= (v.x < 0.0f) ? (1u << c) : 0u;
        b1 |= (v.y < 0.0f) ? (1u << c) : 0u;
        b2 |= (v.z < 0.0f) ? (1u << c) : 0u;
        b3 |= (v.w < 0.0f) ? (1u << c) : 0u;
    }
    *reinterpret_cast<uint4*>(xbits + p) = make_uint4(b0, b1, b2, b3);
}

// 1 px/thread (VGPR ~32, high occupancy), linear pixel indexing so each wave
// covers 64 consecutive columns of one row: all x loads, bit loads, and out
// stores are 256 B/wave contiguous. Bits come from the precomputed global
// xbits (3.3 MB, L2-resident) -- no halo re-pack, no LDS.
// Branch-free interior formula for all pixels; image-border pixels are wrong
// (clamped neighborhood) and are overwritten by border_fix afterwards.
__global__ __launch_bounds__(256) void fused_main(const float* __restrict__ x,
                                                  const uint32_t* __restrict__ wsu,
                                                  float* __restrict__ out) {
    const float* wf = (const float*)wsu;
    int p   = blockIdx.x * blockDim.x + threadIdx.x;  // pixel index, exact grid
    int n   = p / HW;
    int rem = p % HW;
    int h   = rem / W;
    int w   = rem % W;

    const uint32_t* xbn = wsu + XBOFF + n * HW;

    int hm1 = (h > 0) ? h - 1 : 0;
    int hp1 = (h < H - 1) ? h + 1 : H - 1;
    int wm1 = (w > 0) ? w - 1 : 0;
    int wp1 = (w < W - 1) ? w + 1 : W - 1;

    uint32_t nb[3][3];
    {
        const uint32_t* r0 = xbn + hm1 * W;
        const uint32_t* r1 = xbn + h   * W;
        const uint32_t* r2 = xbn + hp1 * W;
        nb[0][0] = r0[wm1]; nb[0][1] = r0[w]; nb[0][2] = r0[wp1];
        nb[1][0] = r1[wm1]; nb[1][1] = r1[w]; nb[1][2] = r1[wp1];
        nb[2][0] = r2[wm1]; nb[2][1] = r2[w]; nb[2][2] = r2[wp1];
    }

    const float* xp = x + n * CHW + h * W + w;
    float y[32];
    uint32_t yb = 0;
#pragma unroll
    for (int oc = 0; oc < 32; ++oc) {
        int s = 0;
#pragma unroll
        for (int r = 0; r < 3; ++r)
#pragma unroll
            for (int c = 0; c < 3; ++c)
                s += __popc(nb[r][c] ^ wsu[oc * 9 + r * 3 + c]);  // uniform -> s_load
        float sc = wf[320 + oc], sh = wf[352 + oc];               // uniform -> s_load
        y[oc] = fmaf((float)(288 - 2 * s), sc, sh) + xp[oc * HW];
        yb |= (y[oc] < 0.0f) ? (1u << oc) : 0u;
    }

    float* op = out + n * CHW + h * W + w;
#pragma unroll
    for (int oc = 0; oc < 32; ++oc) {
        float sc = wf[384 + oc], sh = wf[416 + oc];
        int cc = 32 - 2 * __popc(yb ^ wsu[288 + oc]);
        op[oc * HW] = fmaf((float)cc, sc, sh) + y[oc];
    }
}

// Recompute border pixels exactly (true zero-padding masks) from packed bits.
// 636 border pixels per image * 32 images = 20352 threads.
__global__ __launch_bounds__(256) void border_fix(const float* __restrict__ x,
                                                  const uint32_t* __restrict__ wsu,
                                                  float* __restrict__ out) {
    const float* wf = (const float*)wsu;
    int t = blockIdx.x * blockDim.x + threadIdx.x;
    if (t >= NB * 636) return;
    int n = t / 636, idx = t % 636;
    int h, w;
    if (idx < 160)      { h = 0;         w = idx; }
    else if (idx < 320) { h = H - 1;     w = idx - 160; }
    else if (idx < 478) { h = idx - 319; w = 0; }       // h = 1..158
    else                { h = idx - 477; w = W - 1; }   // h = 1..158

    const uint32_t* xbn = wsu + XBOFF + n * HW;
    uint32_t nb[3][3];
    int m[3][3];
#pragma unroll
    for (int r = 0; r < 3; ++r) {
        int hh = h + r - 1;
        bool rok = (hh >= 0) && (hh < H);
#pragma unroll
        for (int c = 0; c < 3; ++c) {
            int ww = w + c - 1;
            bool ok = rok && (ww >= 0) && (ww < W);
            m[r][c]  = ok ? -1 : 0;
            nb[r][c] = ok ? xbn[hh * W + ww] : 0u;
        }
    }

    const float* xp = x + n * CHW + h * W + w;
    float y[32];
    uint32_t yb = 0;
#pragma unroll
    for (int oc = 0; oc < 32; ++oc) {
        int s = 0;   // true conv value (masked taps contribute 0)
#pragma unroll
        for (int r = 0; r < 3; ++r) {
#pragma unroll
            for (int c = 0; c < 3; ++c) {
                uint32_t wv = wsu[oc * 9 + r * 3 + c];
                s += (32 - 2 * __popc(nb[r][c] ^ wv)) & m[r][c];
            }
        }
        float sc = wf[320 + oc], sh = wf[352 + oc];
        y[oc] = fmaf((float)s, sc, sh) + xp[oc * HW];
        yb |= (y[oc] < 0.0f) ? (1u << oc) : 0u;
    }
    float* op = out + n * CHW + h * W + w;
#pragma unroll
    for (int oc = 0; oc < 32; ++oc) {
        float sc = wf[384 + oc], sh = wf[416 + oc];
        int cc = 32 - 2 * __popc(yb ^ wsu[288 + oc]);
        op[oc * HW] = fmaf((float)cc, sc, sh) + y[oc];
    }
}

extern "C" void kernel_launch(void* const* d_in, const int* in_sizes, int n_in,
                              void* d_out, int out_size, void* d_ws, size_t ws_size,
                              hipStream_t stream) {
    const float* x  = (const float*)d_in[0];
    const float* w3 = (const float*)d_in[1];
    const float* g3 = (const float*)d_in[2];
    const float* b3 = (const float*)d_in[3];
    const float* m3 = (const float*)d_in[4];
    const float* v3 = (const float*)d_in[5];
    const float* w1 = (const float*)d_in[6];
    const float* g1 = (const float*)d_in[7];
    const float* b1 = (const float*)d_in[8];
    const float* m1 = (const float*)d_in[9];
    const float* v1 = (const float*)d_in[10];
    float* out = (float*)d_out;
    uint32_t* wsu = (uint32_t*)d_ws;

    pack_params<<<1, 320, 0, stream>>>(w3, g3, b3, m3, v3, w1, g1, b1, m1, v1, wsu);
    pack_x<<<NPIX / 4 / 256, 256, 0, stream>>>(x, wsu + XBOFF);
    fused_main<<<NPIX / 256, 256, 0, stream>>>(x, wsu, out);
    border_fix<<<(NB * 636 + 255) / 256, 256, 0, stream>>>(x, wsu, out);
}